// Round 8
// baseline (1024.615 us; speedup 1.0000x reference)
//
#include <hip/hip_runtime.h>

// Bahdanau attention: B=32, T=512, S=1024, H=512, fp32.
// out = context [B,T,H] ++ attn_last [B,S]
// ws  = Q [B,T,H] ++ E4 [B,H/4,S,4]; Q = e^{2*Wsq}, E = e^{2*Whe} (clamped
// exp2 in matmul epilogues). Score trick: softmax shift-invariance =>
// score' = sum_h (-2 v_h) / (1 + Q*E); h-quads combined by a reciprocal tree:
// 14 VALU + 1 rcp per 4 elements. NOTE (r6/r7 lessons): no register arrays,
// no packed-f32 (gfx950 has no fp32 dual-issue) -> scalar tree, named vars.

constexpr int B = 32, T = 512, S = 1024, H = 512;
constexpr int TT = 4;  // timesteps per attn block
constexpr float C2LOG2E = 2.88539008177792681f;  // 2*log2(e)

typedef float vf4 __attribute__((ext_vector_type(4)));

#define DEVI __device__ __forceinline__

DEVI vf4 exp2clampv(vf4 x) {
  vf4 r;
#pragma unroll
  for (int i = 0; i < 4; ++i)
    r[i] = __builtin_amdgcn_exp2f(fminf(fmaxf(x[i], -15.f), 15.f));
  return r;
}

// C = exp2(clamp(scale * A[M][512] * W[512][512]^T)). TRANS=false: C[m][o].
// TRANS=true: C as [b][o/4][s][4], m = b*S + s; fully-masked s-tiles skipped.
template <bool TRANS>
__global__ __launch_bounds__(256)
void matmul_nt_kernel(const float* __restrict__ A, const float* __restrict__ W,
                      float* __restrict__ Cout, float scale, const int* __restrict__ lens) {
  constexpr int K = H, N = H, BM = 64, BN = 64, BK = 16;
  __shared__ __align__(16) float As[BK][BM + 4];
  __shared__ __align__(16) float Bs[BK][BN + 4];
  const int nbx = N / BN;  // 8
  const int bx = blockIdx.x % nbx, by = blockIdx.x / nbx;
  const int row0 = by * BM, col0 = bx * BN;
  if (TRANS) {  // rows row0..row0+63 are one batch; skip if fully masked
    if ((row0 % S) >= lens[row0 / S]) return;
  }
  const int tid = threadIdx.x;
  const int tx = tid & 15, ty = tid >> 4;
  const int lr = tid >> 2, lk = (tid & 3) * 4;
  float acc[4][4] = {};
  for (int k0 = 0; k0 < K; k0 += BK) {
    float4 av = *(const float4*)&A[(size_t)(row0 + lr) * K + k0 + lk];
    float4 wv = *(const float4*)&W[(size_t)(col0 + lr) * K + k0 + lk];
    __syncthreads();
    As[lk + 0][lr] = av.x; As[lk + 1][lr] = av.y; As[lk + 2][lr] = av.z; As[lk + 3][lr] = av.w;
    Bs[lk + 0][lr] = wv.x; Bs[lk + 1][lr] = wv.y; Bs[lk + 2][lr] = wv.z; Bs[lk + 3][lr] = wv.w;
    __syncthreads();
#pragma unroll
    for (int k = 0; k < BK; ++k) {
      float4 a4 = *(const float4*)&As[k][ty * 4];
      float4 w4 = *(const float4*)&Bs[k][tx * 4];
      float a[4] = {a4.x, a4.y, a4.z, a4.w};
      float w[4] = {w4.x, w4.y, w4.z, w4.w};
#pragma unroll
      for (int i = 0; i < 4; ++i)
#pragma unroll
        for (int j = 0; j < 4; ++j) acc[i][j] = __builtin_fmaf(a[i], w[j], acc[i][j]);
    }
  }
  if (!TRANS) {
#pragma unroll
    for (int i = 0; i < 4; ++i) {
      vf4 o = {acc[i][0] * scale, acc[i][1] * scale, acc[i][2] * scale, acc[i][3] * scale};
      *(vf4*)&Cout[(size_t)(row0 + ty * 4 + i) * N + col0 + tx * 4] = exp2clampv(o);
    }
  } else {
    const int b = row0 / S;
    const int sl = (row0 % S) + ty * 4;
    // E4[b][h4][s][c]: addr = b*H*S + h4*4S + s*4 + c, h4 = col0/4 + tx, c = j
    float* base = Cout + (size_t)b * H * S + (size_t)((col0 >> 2) + tx) * (4 * S);
#pragma unroll
    for (int i = 0; i < 4; ++i) {
      vf4 o = {acc[i][0] * scale, acc[i][1] * scale, acc[i][2] * scale, acc[i][3] * scale};
      *(vf4*)&base[(size_t)(sl + i) * 4] = exp2clampv(o);
    }
  }
}

// Fused: scores -> masked softmax -> context. One block = (b, 4 timesteps).
__global__ __launch_bounds__(256, 6)
void attn_fused_kernel(const float* __restrict__ wsq, const float* __restrict__ wheT,
                       const float* __restrict__ enc, const float* __restrict__ v,
                       const int* __restrict__ lens, float* __restrict__ out) {
  __shared__ __align__(16) float s_wsq[TT][H];  // 8 KB : Q rows
  __shared__ __align__(16) float s_v[H];        // 2 KB : -2*v
  __shared__ __align__(16) float s_sc[TT][S];   // 16 KB: scores, then p in place
  __shared__ float s_rs[TT];
  __shared__ long long s_w[32];
  __shared__ int s_bsel;

  const int tid = threadIdx.x;
  const int xcd = blockIdx.x & 7;     // dispatch round-robin heuristic
  const int j = blockIdx.x >> 3;      // 0..511
  const int slot = j >> 7;            // 0..3: which of this XCD's 4 batches
  const int tt = j & 127;             // 0..127 t-tile within batch

  // Runtime snake load-balance: rank batches by len (desc), XCD x gets ranks
  // {x, 15-x, 16+x, 31-x} -> balanced work, batch-major locality.
  if (tid < 32) s_w[tid] = ((long long)lens[tid] << 8) + tid;  // unique key
  __syncthreads();
  if (tid < 32) {
    long long wb = s_w[tid];
    int rank = 0;
#pragma unroll
    for (int b2 = 0; b2 < 32; ++b2) rank += (s_w[b2] > wb);
    int myrank = slot * 8 + ((slot & 1) ? (7 - xcd) : xcd);
    if (rank == myrank) s_bsel = tid;
  }
  // stage -2*v while the select settles
  if (tid >= 128) {
    int c = (tid - 128) * 4;
    vf4 t4 = *(const vf4*)&v[c];
    *(vf4*)&s_v[c] = t4 * -2.0f;
  }
  __syncthreads();
  const int b = __builtin_amdgcn_readfirstlane(s_bsel);
  const int len = lens[b];

  {  // stage Q rows for this t-tile
    int r = tid >> 6, c0 = (tid & 63) * 4;
#pragma unroll
    for (int u = 0; u < 2; ++u) {
      int c = c0 + u * 256;
      *(vf4*)&s_wsq[r][c] = *(const vf4*)&wsq[((size_t)b * T + tt * TT + r) * H + c];
    }
  }
  __syncthreads();

  // ---- Phase A: scores over 64-s strips; wave w takes strips k=(w+tt) mod 4.
  // Thread owns one s for all 4 t; h-quads via reciprocal tree; E prefetched
  // 2 iterations ahead (named vars only -- no register arrays). ----
  {
    const int wv = tid >> 6, lane = tid & 63;
    const int NS = (len + 63) >> 6;  // strips actually needed
    const float* e4b = wheT + (size_t)b * H * S;  // [h4][s][4]
    for (int k = (wv + tt) & 3; k < NS; k += 4) {
      const int s = k * 64 + lane;
      const float* ep = e4b + (size_t)s * 4;
      float ac0 = 0.f, ac1 = 0.f, ac2 = 0.f, ac3 = 0.f;
      vf4 e_c = *(const vf4*)ep;
      vf4 e_n1 = *(const vf4*)(ep + (size_t)(S * 4));
      vf4 e_n2;
#pragma unroll 2
      for (int h4 = 0; h4 < H / 4; ++h4) {
        if (h4 + 2 < H / 4) e_n2 = *(const vf4*)(ep + (size_t)(h4 + 2) * (S * 4));
        vf4 e = e_c;
        vf4 vv = *(const vf4*)&s_v[h4 * 4];
        {
          vf4 q = *(const vf4*)&s_wsq[0][h4 * 4];
          float a0 = __builtin_fmaf(q[0], e[0], 1.0f);
          float a1 = __builtin_fmaf(q[1], e[1], 1.0f);
          float a2 = __builtin_fmaf(q[2], e[2], 1.0f);
          float a3 = __builtin_fmaf(q[3], e[3], 1.0f);
          float d01 = a0 * a1, d23 = a2 * a3;
          float n01 = __builtin_fmaf(vv[1], a0, vv[0] * a1);
          float n23 = __builtin_fmaf(vv[3], a2, vv[2] * a3);
          float d = d01 * d23;
          float n = __builtin_fmaf(n23, d01, n01 * d23);
          ac0 = __builtin_fmaf(n, __builtin_amdgcn_rcpf(d), ac0);
        }
        {
          vf4 q = *(const vf4*)&s_wsq[1][h4 * 4];
          float a0 = __builtin_fmaf(q[0], e[0], 1.0f);
          float a1 = __builtin_fmaf(q[1], e[1], 1.0f);
          float a2 = __builtin_fmaf(q[2], e[2], 1.0f);
          float a3 = __builtin_fmaf(q[3], e[3], 1.0f);
          float d01 = a0 * a1, d23 = a2 * a3;
          float n01 = __builtin_fmaf(vv[1], a0, vv[0] * a1);
          float n23 = __builtin_fmaf(vv[3], a2, vv[2] * a3);
          float d = d01 * d23;
          float n = __builtin_fmaf(n23, d01, n01 * d23);
          ac1 = __builtin_fmaf(n, __builtin_amdgcn_rcpf(d), ac1);
        }
        {
          vf4 q = *(const vf4*)&s_wsq[2][h4 * 4];
          float a0 = __builtin_fmaf(q[0], e[0], 1.0f);
          float a1 = __builtin_fmaf(q[1], e[1], 1.0f);
          float a2 = __builtin_fmaf(q[2], e[2], 1.0f);
          float a3 = __builtin_fmaf(q[3], e[3], 1.0f);
          float d01 = a0 * a1, d23 = a2 * a3;
          float n01 = __builtin_fmaf(vv[1], a0, vv[0] * a1);
          float n23 = __builtin_fmaf(vv[3], a2, vv[2] * a3);
          float d = d01 * d23;
          float n = __builtin_fmaf(n23, d01, n01 * d23);
          ac2 = __builtin_fmaf(n, __builtin_amdgcn_rcpf(d), ac2);
        }
        {
          vf4 q = *(const vf4*)&s_wsq[3][h4 * 4];
          float a0 = __builtin_fmaf(q[0], e[0], 1.0f);
          float a1 = __builtin_fmaf(q[1], e[1], 1.0f);
          float a2 = __builtin_fmaf(q[2], e[2], 1.0f);
          float a3 = __builtin_fmaf(q[3], e[3], 1.0f);
          float d01 = a0 * a1, d23 = a2 * a3;
          float n01 = __builtin_fmaf(vv[1], a0, vv[0] * a1);
          float n23 = __builtin_fmaf(vv[3], a2, vv[2] * a3);
          float d = d01 * d23;
          float n = __builtin_fmaf(n23, d01, n01 * d23);
          ac3 = __builtin_fmaf(n, __builtin_amdgcn_rcpf(d), ac3);
        }
        e_c = e_n1;
        e_n1 = e_n2;
      }
      s_sc[0][s] = ac0; s_sc[1][s] = ac1; s_sc[2][s] = ac2; s_sc[3][s] = ac3;
    }
  }
  __syncthreads();

  // ---- Phase B: masked softmax; wave w handles row w ----
  {
    const int tr = tid >> 6, lane = tid & 63;
    float vals[S / 64], ps[S / 64];
    float m = -3.0e38f;
#pragma unroll
    for (int i = 0; i < S / 64; ++i) {
      int s = lane + 64 * i;
      vals[i] = s_sc[tr][s];
      if (s < len) m = fmaxf(m, vals[i]);
    }
#pragma unroll
    for (int o = 1; o < 64; o <<= 1) m = fmaxf(m, __shfl_xor(m, o, 64));
    float sum = 0.f;
#pragma unroll
    for (int i = 0; i < S / 64; ++i) {
      int s = lane + 64 * i;
      float p = (s < len) ? __builtin_amdgcn_exp2f((vals[i] - m) * 1.44269504088896341f) : 0.f;
      ps[i] = p;
      sum += p;
    }
#pragma unroll
    for (int o = 1; o < 64; o <<= 1) sum += __shfl_xor(sum, o, 64);
    float rs = 1.0f / sum;
#pragma unroll
    for (int i = 0; i < S / 64; ++i) s_sc[tr][lane + 64 * i] = ps[i];
    if (lane == 0) s_rs[tr] = rs;
    if (tt == T / TT - 1 && tr == TT - 1) {  // last timestep: attention weights
#pragma unroll
      for (int i = 0; i < S / 64; ++i)
        out[(size_t)B * T * H + (size_t)b * S + lane + 64 * i] = ps[i] * rs;
    }
  }
  __syncthreads();

  // ---- Phase C: ctx[t][h] = sum_{s<len} p[t][s] * enc[b][s][h]; wave = t ----
  {
    const int tg = tid >> 6, lane = tid & 63;
    const int h0 = lane * 4, h1 = 256 + lane * 4;
    float acc[8] = {};
    const float* encb = enc + (size_t)b * S * H;
    const int len4 = (len + 3) & ~3;  // p == 0 beyond len, safe to over-read
    for (int s0 = 0; s0 < len4; s0 += 4) {
      vf4 p4 = *(const vf4*)&s_sc[tg][s0];
#pragma unroll
      for (int k = 0; k < 4; ++k) {
        const float* er = encb + (size_t)(s0 + k) * H;
        float4 e0 = *(const float4*)(er + h0);
        float4 e1 = *(const float4*)(er + h1);
        float ev[8] = {e0.x, e0.y, e0.z, e0.w, e1.x, e1.y, e1.z, e1.w};
#pragma unroll
        for (int q = 0; q < 8; ++q) acc[q] = __builtin_fmaf(p4[k], ev[q], acc[q]);
      }
    }
    const float rs = s_rs[tg];
    const size_t base = ((size_t)b * T + tt * TT + tg) * H;
    float4 o;
    o = make_float4(acc[0] * rs, acc[1] * rs, acc[2] * rs, acc[3] * rs);
    *(float4*)&out[base + h0] = o;
    o = make_float4(acc[4] * rs, acc[5] * rs, acc[6] * rs, acc[7] * rs);
    *(float4*)&out[base + h1] = o;
  }
}

extern "C" void kernel_launch(void* const* d_in, const int* in_sizes, int n_in,
                              void* d_out, int out_size, void* d_ws, size_t ws_size,
                              hipStream_t stream) {
  const float* query = (const float*)d_in[0];  // [B,T,H]
  const float* enc   = (const float*)d_in[1];  // [B,S,H]
  const int*   lens  = (const int*)d_in[2];    // [B]
  const float* Ws    = (const float*)d_in[3];  // [H,H]
  const float* Wh    = (const float*)d_in[4];  // [H,H]
  const float* v     = (const float*)d_in[5];  // [H]
  float* out = (float*)d_out;
  float* wsq  = (float*)d_ws;                  // [B,T,H] = Q
  float* wheT = wsq + (size_t)B * T * H;       // [B,H/4,S,4] = E4

  matmul_nt_kernel<false><<<dim3((B * T / 64) * 8), 256, 0, stream>>>(query, Ws, wsq, C2LOG2E, nullptr);
  matmul_nt_kernel<true><<<dim3((B * S / 64) * 8), 256, 0, stream>>>(enc, Wh, wheT, C2LOG2E, lens);
  attn_fused_kernel<<<dim3(B * (T / TT)), 256, 0, stream>>>(wsq, wheT, enc, v, lens, out);
}

// Round 9
// 932.099 us; speedup vs baseline: 1.0993x; 1.0993x over previous
//
#include <hip/hip_runtime.h>

// Bahdanau attention: B=32, T=512, S=1024, H=512, fp32.
// out = context [B,T,H] ++ attn_last [B,S]
// ws  = Q [B,T,H] ++ E4 [B,H/4,S,4]; Q = e^{2*Wsq}, E = e^{2*Whe} (clamped
// exp2 in matmul epilogues). Softmax shift-invariance => score' =
// sum_h (-2 v_h)/(1 + Q*E); h-quads via reciprocal tree (14 VALU + 1 rcp / 4).
// r8 lesson: Phase A was LDS-read-throughput-bound (5 ds_read_b128 per 60
// VALU = 2x LDS oversubscription). Fix: q/v are wave-uniform -> load via
// uniform pointers (s_load, scalar cache) -> zero steady-state LDS reads;
// drop q/v staging -> LDS 16.6KB -> 8 blocks/CU.

constexpr int B = 32, T = 512, S = 1024, H = 512;
constexpr int TT = 4;  // timesteps per attn block
constexpr float C2LOG2E = 2.88539008177792681f;  // 2*log2(e)

typedef float vf4 __attribute__((ext_vector_type(4)));

#define DEVI __device__ __forceinline__

DEVI vf4 exp2clampv(vf4 x) {
  vf4 r;
#pragma unroll
  for (int i = 0; i < 4; ++i)
    r[i] = __builtin_amdgcn_exp2f(fminf(fmaxf(x[i], -15.f), 15.f));
  return r;
}

// C = exp2(clamp(scale * A[M][512] * W[512][512]^T)). TRANS=false: C[m][o].
// TRANS=true: C as [b][o/4][s][4], m = b*S + s; fully-masked s-tiles skipped.
template <bool TRANS>
__global__ __launch_bounds__(256)
void matmul_nt_kernel(const float* __restrict__ A, const float* __restrict__ W,
                      float* __restrict__ Cout, float scale, const int* __restrict__ lens) {
  constexpr int K = H, N = H, BM = 64, BN = 64, BK = 16;
  __shared__ __align__(16) float As[BK][BM + 4];
  __shared__ __align__(16) float Bs[BK][BN + 4];
  const int nbx = N / BN;  // 8
  const int bx = blockIdx.x % nbx, by = blockIdx.x / nbx;
  const int row0 = by * BM, col0 = bx * BN;
  if (TRANS) {  // rows row0..row0+63 are one batch; skip if fully masked
    if ((row0 % S) >= lens[row0 / S]) return;
  }
  const int tid = threadIdx.x;
  const int tx = tid & 15, ty = tid >> 4;
  const int lr = tid >> 2, lk = (tid & 3) * 4;
  float acc[4][4] = {};
  for (int k0 = 0; k0 < K; k0 += BK) {
    float4 av = *(const float4*)&A[(size_t)(row0 + lr) * K + k0 + lk];
    float4 wv = *(const float4*)&W[(size_t)(col0 + lr) * K + k0 + lk];
    __syncthreads();
    As[lk + 0][lr] = av.x; As[lk + 1][lr] = av.y; As[lk + 2][lr] = av.z; As[lk + 3][lr] = av.w;
    Bs[lk + 0][lr] = wv.x; Bs[lk + 1][lr] = wv.y; Bs[lk + 2][lr] = wv.z; Bs[lk + 3][lr] = wv.w;
    __syncthreads();
#pragma unroll
    for (int k = 0; k < BK; ++k) {
      float4 a4 = *(const float4*)&As[k][ty * 4];
      float4 w4 = *(const float4*)&Bs[k][tx * 4];
      float a[4] = {a4.x, a4.y, a4.z, a4.w};
      float w[4] = {w4.x, w4.y, w4.z, w4.w};
#pragma unroll
      for (int i = 0; i < 4; ++i)
#pragma unroll
        for (int j = 0; j < 4; ++j) acc[i][j] = __builtin_fmaf(a[i], w[j], acc[i][j]);
    }
  }
  if (!TRANS) {
#pragma unroll
    for (int i = 0; i < 4; ++i) {
      vf4 o = {acc[i][0] * scale, acc[i][1] * scale, acc[i][2] * scale, acc[i][3] * scale};
      *(vf4*)&Cout[(size_t)(row0 + ty * 4 + i) * N + col0 + tx * 4] = exp2clampv(o);
    }
  } else {
    const int b = row0 / S;
    const int sl = (row0 % S) + ty * 4;
    // E4[b][h4][s][c]: addr = b*H*S + h4*4S + s*4 + c, h4 = col0/4 + tx, c = j
    float* base = Cout + (size_t)b * H * S + (size_t)((col0 >> 2) + tx) * (4 * S);
#pragma unroll
    for (int i = 0; i < 4; ++i) {
      vf4 o = {acc[i][0] * scale, acc[i][1] * scale, acc[i][2] * scale, acc[i][3] * scale};
      *(vf4*)&base[(size_t)(sl + i) * 4] = exp2clampv(o);
    }
  }
}

// acc += sum_{i<4} vv[i] / (1 + q[i]*e[i]) via single-rcp reciprocal tree.
DEVI void tree4(float& acc, vf4 q, vf4 vv, vf4 e) {
  float a0 = __builtin_fmaf(q[0], e[0], 1.0f);
  float a1 = __builtin_fmaf(q[1], e[1], 1.0f);
  float a2 = __builtin_fmaf(q[2], e[2], 1.0f);
  float a3 = __builtin_fmaf(q[3], e[3], 1.0f);
  float d01 = a0 * a1, d23 = a2 * a3;
  float n01 = __builtin_fmaf(vv[1], a0, vv[0] * a1);
  float n23 = __builtin_fmaf(vv[3], a2, vv[2] * a3);
  float d = d01 * d23;
  float n = __builtin_fmaf(n23, d01, n01 * d23);
  acc = __builtin_fmaf(n, __builtin_amdgcn_rcpf(d), acc);
}

// Fused: scores -> masked softmax -> context. One block = (b, 4 timesteps).
__global__ __launch_bounds__(256, 8)
void attn_fused_kernel(const float* __restrict__ wsq, const float* __restrict__ wheT,
                       const float* __restrict__ enc, const float* __restrict__ v,
                       const int* __restrict__ lens, float* __restrict__ out) {
  __shared__ __align__(16) float s_sc[TT][S];  // 16 KB: scores, then p in place
  __shared__ float s_rs[TT];
  __shared__ long long s_w[32];
  __shared__ int s_bsel;

  const int tid = threadIdx.x;
  const int xcd = blockIdx.x & 7;     // dispatch round-robin heuristic
  const int j = blockIdx.x >> 3;      // 0..511
  const int slot = j >> 7;            // 0..3: which of this XCD's 4 batches
  const int tt = j & 127;             // 0..127 t-tile within batch

  // Runtime snake load-balance: rank batches by len (desc), XCD x gets ranks
  // {x, 15-x, 16+x, 31-x} -> balanced work, batch-major locality.
  if (tid < 32) s_w[tid] = ((long long)lens[tid] << 8) + tid;  // unique key
  __syncthreads();
  if (tid < 32) {
    long long wb = s_w[tid];
    int rank = 0;
#pragma unroll
    for (int b2 = 0; b2 < 32; ++b2) rank += (s_w[b2] > wb);
    int myrank = slot * 8 + ((slot & 1) ? (7 - xcd) : xcd);
    if (rank == myrank) s_bsel = tid;
  }
  __syncthreads();
  const int b = __builtin_amdgcn_readfirstlane(s_bsel);
  const int len = lens[b];

  // ---- Phase A: 64-s strips; wave w takes strips k=(w+tt) mod 4. Thread owns
  // one s for all 4 t. q/v are wave-uniform -> scalar loads (no LDS). ----
  {
    const int wv = tid >> 6, lane = tid & 63;
    const int NS = (len + 63) >> 6;  // strips actually needed
    const float* e4b = wheT + (size_t)b * H * S;            // [h4][s][4]
    const float* qb = wsq + ((size_t)b * T + (size_t)tt * TT) * H;  // uniform
    for (int k = (wv + tt) & 3; k < NS; k += 4) {
      const int s = k * 64 + lane;
      const float* ep = e4b + (size_t)s * 4;
      float ac0 = 0.f, ac1 = 0.f, ac2 = 0.f, ac3 = 0.f;
      vf4 e_c = *(const vf4*)ep;
      vf4 e_n = e_c;
      for (int h4 = 0; h4 < H / 4; ++h4) {
        if (h4 + 1 < H / 4) e_n = *(const vf4*)(ep + (size_t)(h4 + 1) * (S * 4));
        vf4 e = e_c;
        vf4 vv = *(const vf4*)(v + h4 * 4);                 // uniform -> s_load
        tree4(ac0, *(const vf4*)(qb + 0 * H + h4 * 4), vv, e);
        tree4(ac1, *(const vf4*)(qb + 1 * H + h4 * 4), vv, e);
        tree4(ac2, *(const vf4*)(qb + 2 * H + h4 * 4), vv, e);
        tree4(ac3, *(const vf4*)(qb + 3 * H + h4 * 4), vv, e);
        e_c = e_n;
      }
      s_sc[0][s] = -2.0f * ac0;
      s_sc[1][s] = -2.0f * ac1;
      s_sc[2][s] = -2.0f * ac2;
      s_sc[3][s] = -2.0f * ac3;
    }
  }
  __syncthreads();

  // ---- Phase B: masked softmax; wave w handles row w ----
  {
    const int tr = tid >> 6, lane = tid & 63;
    float vals[S / 64], ps[S / 64];
    float m = -3.0e38f;
#pragma unroll
    for (int i = 0; i < S / 64; ++i) {
      int s = lane + 64 * i;
      vals[i] = s_sc[tr][s];
      if (s < len) m = fmaxf(m, vals[i]);
    }
#pragma unroll
    for (int o = 1; o < 64; o <<= 1) m = fmaxf(m, __shfl_xor(m, o, 64));
    float sum = 0.f;
#pragma unroll
    for (int i = 0; i < S / 64; ++i) {
      int s = lane + 64 * i;
      float p = (s < len) ? __builtin_amdgcn_exp2f((vals[i] - m) * 1.44269504088896341f) : 0.f;
      ps[i] = p;
      sum += p;
    }
#pragma unroll
    for (int o = 1; o < 64; o <<= 1) sum += __shfl_xor(sum, o, 64);
    float rs = 1.0f / sum;
#pragma unroll
    for (int i = 0; i < S / 64; ++i) s_sc[tr][lane + 64 * i] = ps[i];
    if (lane == 0) s_rs[tr] = rs;
    if (tt == T / TT - 1 && tr == TT - 1) {  // last timestep: attention weights
#pragma unroll
      for (int i = 0; i < S / 64; ++i)
        out[(size_t)B * T * H + (size_t)b * S + lane + 64 * i] = ps[i] * rs;
    }
  }
  __syncthreads();

  // ---- Phase C: ctx[t][h] = sum_{s<len} p[t][s] * enc[b][s][h]; wave = t ----
  {
    const int tg = tid >> 6, lane = tid & 63;
    const int h0 = lane * 4, h1 = 256 + lane * 4;
    float acc[8] = {};
    const float* encb = enc + (size_t)b * S * H;
    const int len4 = (len + 3) & ~3;  // p == 0 beyond len, safe to over-read
    for (int s0 = 0; s0 < len4; s0 += 4) {
      vf4 p4 = *(const vf4*)&s_sc[tg][s0];
#pragma unroll
      for (int k = 0; k < 4; ++k) {
        const float* er = encb + (size_t)(s0 + k) * H;
        float4 e0 = *(const float4*)(er + h0);
        float4 e1 = *(const float4*)(er + h1);
        float ev[8] = {e0.x, e0.y, e0.z, e0.w, e1.x, e1.y, e1.z, e1.w};
#pragma unroll
        for (int q = 0; q < 8; ++q) acc[q] = __builtin_fmaf(p4[k], ev[q], acc[q]);
      }
    }
    const float rs = s_rs[tg];
    const size_t base = ((size_t)b * T + tt * TT + tg) * H;
    float4 o;
    o = make_float4(acc[0] * rs, acc[1] * rs, acc[2] * rs, acc[3] * rs);
    *(float4*)&out[base + h0] = o;
    o = make_float4(acc[4] * rs, acc[5] * rs, acc[6] * rs, acc[7] * rs);
    *(float4*)&out[base + h1] = o;
  }
}

extern "C" void kernel_launch(void* const* d_in, const int* in_sizes, int n_in,
                              void* d_out, int out_size, void* d_ws, size_t ws_size,
                              hipStream_t stream) {
  const float* query = (const float*)d_in[0];  // [B,T,H]
  const float* enc   = (const float*)d_in[1];  // [B,S,H]
  const int*   lens  = (const int*)d_in[2];    // [B]
  const float* Ws    = (const float*)d_in[3];  // [H,H]
  const float* Wh    = (const float*)d_in[4];  // [H,H]
  const float* v     = (const float*)d_in[5];  // [H]
  float* out = (float*)d_out;
  float* wsq  = (float*)d_ws;                  // [B,T,H] = Q
  float* wheT = wsq + (size_t)B * T * H;       // [B,H/4,S,4] = E4

  matmul_nt_kernel<false><<<dim3((B * T / 64) * 8), 256, 0, stream>>>(query, Ws, wsq, C2LOG2E, nullptr);
  matmul_nt_kernel<true><<<dim3((B * S / 64) * 8), 256, 0, stream>>>(enc, Wh, wheT, C2LOG2E, lens);
  attn_fused_kernel<<<dim3(B * (T / TT)), 256, 0, stream>>>(wsq, wheT, enc, v, lens, out);
}